// Round 10
// baseline (219.839 us; speedup 1.0000x reference)
//
#include <hip/hip_runtime.h>
#include <math.h>

#define B_ 32
#define L_ 512
#define D_ 512
#define H_ 512

typedef unsigned short u16;
typedef _Float16 h16;
typedef h16 half8 __attribute__((ext_vector_type(8)));
typedef float f32x4 __attribute__((ext_vector_type(4)));

// chunk swizzle: 16B chunks within a 64B LDS row, XOR by (row>>1)&3.
#define SW(r, c) ((c) ^ (((r) >> 1) & 3))

typedef __attribute__((address_space(1))) void gvoid;
typedef __attribute__((address_space(3))) void svoid;
__device__ __forceinline__ void async_cp16(const void* g, void* l) {
    __builtin_amdgcn_global_load_lds((gvoid*)g, (svoid*)l, 16, 0, 0);
}

__device__ __forceinline__ u16 f2h(float x) {
    h16 h = (h16)x;
    u16 r;
    __builtin_memcpy(&r, &h, 2);
    return r;
}
__device__ __forceinline__ float h2f(u16 u) {
    h16 h;
    __builtin_memcpy(&h, &u, 2);
    return (float)h;
}
// tanh(x) = 1 - 2/(exp(2x)+1); exact at +-inf, err < 2e-6 vs libm
__device__ __forceinline__ float fast_tanh(float x) {
    return 1.0f - 2.0f / (__expf(2.0f * x) + 1.0f);
}

// XCD-aware decodes (round-robin heuristic: block n -> XCD n&7).
__device__ __forceinline__ void xcd_decode16(int n, int& z, int& tile) {
    int xcd = n & 7, w = n >> 3;
    z = xcd + 8 * (w >> 4);
    tile = w & 15;
}
__device__ __forceinline__ void xcd_decode8(int n, int& z, int& tile) {
    int xcd = n & 7, w = n >> 3;
    z = xcd + 8 * (w >> 3);
    tile = w & 7;
}

// ---------------------------------------------------------------------------
// one dispatch: fp32->fp16 convert(+transpose) for I (z<32), J (32<=z<64),
// W (z==64, transposed only). z==64 blocks also zero the output buffer.
// ---------------------------------------------------------------------------
__global__ __launch_bounds__(256) void cvt_all(const float* __restrict__ I,
                                               const float* __restrict__ Jm,
                                               const float* __restrict__ W,
                                               u16* __restrict__ Ih, u16* __restrict__ IhT,
                                               u16* __restrict__ Jh, u16* __restrict__ JhT,
                                               u16* __restrict__ WT,
                                               float* __restrict__ out) {
    const int z = blockIdx.z;
    const float* src;
    u16* h;
    u16* hT;
    size_t base;
    if (z < 32) {
        src = I; h = Ih; hT = IhT; base = (size_t)z * 512 * 512;
    } else if (z < 64) {
        src = Jm; h = Jh; hT = JhT; base = (size_t)(z - 32) * 512 * 512;
    } else {
        src = W; h = nullptr; hT = WT; base = 0;
        out[(blockIdx.y * 8 + blockIdx.x) * 256 + threadIdx.x] = 0.0f;
    }
    const int r0 = blockIdx.y * 64, c0 = blockIdx.x * 64;
    __shared__ u16 t[64][66];
    const int tid = threadIdx.x;
    const int tr = tid >> 4, tc4 = (tid & 15) * 4;
#pragma unroll
    for (int rep = 0; rep < 4; ++rep) {
        int r = rep * 16 + tr;
        f32x4 v = *(const f32x4*)(src + base + (size_t)(r0 + r) * 512 + c0 + tc4);
        unsigned h0 = f2h(v[0]), h1 = f2h(v[1]), h2 = f2h(v[2]), h3 = f2h(v[3]);
        if (h)
            *(uint2*)(h + base + (size_t)(r0 + r) * 512 + c0 + tc4) =
                make_uint2(h0 | (h1 << 16), h2 | (h3 << 16));
        t[r][tc4] = (u16)h0; t[r][tc4 + 1] = (u16)h1;
        t[r][tc4 + 2] = (u16)h2; t[r][tc4 + 3] = (u16)h3;
    }
    __syncthreads();
#pragma unroll
    for (int rep = 0; rep < 4; ++rep) {
        int r = rep * 16 + tr;
        unsigned a = t[tc4][r], b = t[tc4 + 1][r], c = t[tc4 + 2][r], d = t[tc4 + 3][r];
        *(uint2*)(hT + base + (size_t)(c0 + r) * 512 + r0 + tc4) =
            make_uint2(a | (b << 16), c | (d << 16));
    }
}

// ---------------------------------------------------------------------------
// score: S = I.J^T fp16 MFMA. Epilogue writes P_un = fp16(exp(S - rtmax)),
// P_unT = fp16(exp(S - ctmax)), + group stat arrays [b][512][8].
// ---------------------------------------------------------------------------
__global__ __launch_bounds__(256, 2) void score_mfma(const u16* __restrict__ Ih,
                                                     const u16* __restrict__ Jh,
                                                     u16* __restrict__ P_un,
                                                     u16* __restrict__ P_unT,
                                                     float* __restrict__ rtmax,
                                                     float* __restrict__ rtsum,
                                                     float* __restrict__ ctmax,
                                                     float* __restrict__ ctsum) {
    int b, tile;
    xcd_decode16(blockIdx.x, b, tile);  // 512 blocks: 32 b x 16 tiles
    const int i0 = (tile >> 2) * 128, j0 = (tile & 3) * 128;
    __shared__ u16 Ah[128 * 32], Bh[128 * 32];
    const int tid = threadIdx.x;
    const int wave = tid >> 6, lane = tid & 63;
    const int wm = (wave >> 1) * 64, wn = (wave & 1) * 64;
    const int lr = lane & 15, q = lane >> 4;
    const size_t boff = (size_t)b * L_ * D_;
    const u16* Ibh = Ih + boff;
    const u16* Jbh = Jh + boff;

    f32x4 acc[4][4] = {};

    for (int k0 = 0; k0 < D_; k0 += 32) {
#pragma unroll
        for (int h = 0; h < 2; ++h) {
            int g = wave * 2 + h;
            int r = g * 16 + (lane >> 2);
            int cg = SW(r, lane & 3);
            async_cp16(Ibh + (size_t)(i0 + r) * D_ + k0 + cg * 8, (char*)Ah + g * 1024);
            async_cp16(Jbh + (size_t)(j0 + r) * D_ + k0 + cg * 8, (char*)Bh + g * 1024);
        }
        __syncthreads();
        half8 af[4], bf[4];
#pragma unroll
        for (int mi = 0; mi < 4; ++mi) {
            int r = wm + mi * 16 + lr;
            af[mi] = *(const half8*)&Ah[r * 32 + SW(r, q) * 8];
        }
#pragma unroll
        for (int ni = 0; ni < 4; ++ni) {
            int r = wn + ni * 16 + lr;
            bf[ni] = *(const half8*)&Bh[r * 32 + SW(r, q) * 8];
        }
#pragma unroll
        for (int mi = 0; mi < 4; ++mi)
#pragma unroll
            for (int ni = 0; ni < 4; ++ni)
                acc[mi][ni] = __builtin_amdgcn_mfma_f32_16x16x32_f16(af[mi], bf[ni], acc[mi][ni], 0, 0, 0);
        __syncthreads();
    }

    // ---- epilogue: group stats + P_un / P_unT ----
    float rm[4][4];
#pragma unroll
    for (int mi = 0; mi < 4; ++mi)
#pragma unroll
        for (int r4 = 0; r4 < 4; ++r4) {
            float t = fmaxf(fmaxf(acc[mi][0][r4], acc[mi][1][r4]),
                            fmaxf(acc[mi][2][r4], acc[mi][3][r4]));
#pragma unroll
            for (int off = 1; off < 16; off <<= 1) t = fmaxf(t, __shfl_xor(t, off));
            rm[mi][r4] = t;
        }
    float cm[4];
#pragma unroll
    for (int ni = 0; ni < 4; ++ni) {
        float u = -1e30f;
#pragma unroll
        for (int mi = 0; mi < 4; ++mi)
#pragma unroll
            for (int r4 = 0; r4 < 4; ++r4) u = fmaxf(u, acc[mi][ni][r4]);
        u = fmaxf(u, __shfl_xor(u, 16));
        u = fmaxf(u, __shfl_xor(u, 32));
        cm[ni] = u;
    }

    u16* Pu_b = P_un + (size_t)b * L_ * L_;
    u16* PuT_b = P_unT + (size_t)b * L_ * L_;
    float rs[4][4] = {};
    float cs[4] = {};
#pragma unroll
    for (int mi = 0; mi < 4; ++mi)
#pragma unroll
        for (int ni = 0; ni < 4; ++ni) {
            int i_base = i0 + wm + mi * 16 + q * 4;
            int j = j0 + wn + ni * 16 + lr;
            unsigned pc[4];
#pragma unroll
            for (int r4 = 0; r4 < 4; ++r4) {
                float er = __expf(acc[mi][ni][r4] - rm[mi][r4]);
                rs[mi][r4] += er;
                Pu_b[(size_t)(i_base + r4) * L_ + j] = f2h(er);
                float ec = __expf(acc[mi][ni][r4] - cm[ni]);
                cs[ni] += ec;
                pc[r4] = f2h(ec);
            }
            *(uint2*)&PuT_b[(size_t)j * L_ + i_base] =
                make_uint2(pc[0] | (pc[1] << 16), pc[2] | (pc[3] << 16));
        }

    const int gr = (j0 + wn) >> 6;
    const int gc = (i0 + wm) >> 6;
#pragma unroll
    for (int mi = 0; mi < 4; ++mi)
#pragma unroll
        for (int r4 = 0; r4 < 4; ++r4) {
            float s = rs[mi][r4];
#pragma unroll
            for (int off = 1; off < 16; off <<= 1) s += __shfl_xor(s, off);
            if (lr == 0) {
                int i = i0 + wm + mi * 16 + q * 4 + r4;
                rtmax[((size_t)b * L_ + i) * 8 + gr] = rm[mi][r4];
                rtsum[((size_t)b * L_ + i) * 8 + gr] = s;
            }
        }
#pragma unroll
    for (int ni = 0; ni < 4; ++ni) {
        float s = cs[ni];
        s += __shfl_xor(s, 16);
        s += __shfl_xor(s, 32);
        if (q == 0) {
            int j = j0 + wn + ni * 16 + lr;
            ctmax[((size_t)b * L_ + j) * 8 + gc] = cm[ni];
            ctsum[((size_t)b * L_ + j) * 8 + gc] = s;
        }
    }
}

// ---------------------------------------------------------------------------
// fused tail: X = |Oh - softmax.V| computed into LDS (64 l-rows x 512 d,
// fp16, pad 520), then immediately agg: out[b,h] += (0.5/L) * sum_l
// tanh(X.W + b). X never touches HBM. 512 blocks (64 zz x 8 l-tiles),
// LDS 80,896 B -> 2 blocks/CU. Waves [2m x 2n]: 32 rows x 64 cols, acc[2][4].
// ---------------------------------------------------------------------------
__global__ __launch_bounds__(256, 2) void fused_tail(const u16* __restrict__ P_un,
                                                     const u16* __restrict__ P_unT,
                                                     const float* __restrict__ rtmax,
                                                     const float* __restrict__ rtsum,
                                                     const float* __restrict__ ctmax,
                                                     const float* __restrict__ ctsum,
                                                     const u16* __restrict__ JhT,
                                                     const u16* __restrict__ IhT,
                                                     const u16* __restrict__ Ih,
                                                     const u16* __restrict__ Jh,
                                                     const u16* __restrict__ Wt,
                                                     const float* __restrict__ bias,
                                                     float* __restrict__ out) {
    int zz, ltile;
    xcd_decode8(blockIdx.x, zz, ltile);  // 512 blocks: 64 zz x 8 l-tiles
    const int side = zz >> 5, b = zz & 31;
    const int l0 = ltile * 64;
    const u16* Pb = (side ? P_unT : P_un) + (size_t)b * L_ * L_;
    const float* tmax = (side ? ctmax : rtmax) + (size_t)b * L_ * 8;
    const float* tsum = (side ? ctsum : rtsum) + (size_t)b * L_ * 8;
    const u16* Vt = (side ? IhT : JhT) + (size_t)b * D_ * L_;
    const u16* Oh = (side ? Jh : Ih) + (size_t)b * L_ * D_;

    __shared__ u16 Xs[64][520];   // 66,560 B; stride 260 dwords = 4 mod 32 banks
    __shared__ u16 As[64 * 32];   // 4 KB: stage-1 P chunk
    __shared__ u16 Bs[128 * 32];  // 8 KB: stage-1 Vt / stage-2 Wt chunk
    __shared__ float sc[8][64];   // 2 KB, transposed (r9 conflict fix)
    const int tid = threadIdx.x;
    const int wave = tid >> 6, lane = tid & 63;
    const int wm = (wave >> 1) * 32, wn = (wave & 1) * 64;
    const int lr = lane & 15, q = lane >> 4;

    // prologue: combine 8 group stats -> per-row scale table (64 rows)
    if (tid < 64) {
        const float* tm = tmax + (size_t)(l0 + tid) * 8;
        const float* ts = tsum + (size_t)(l0 + tid) * 8;
        f32x4 m0 = *(const f32x4*)tm, m1 = *(const f32x4*)(tm + 4);
        f32x4 s0 = *(const f32x4*)ts, s1 = *(const f32x4*)(ts + 4);
        float m = fmaxf(fmaxf(fmaxf(m0[0], m0[1]), fmaxf(m0[2], m0[3])),
                        fmaxf(fmaxf(m1[0], m1[1]), fmaxf(m1[2], m1[3])));
        float e0 = __expf(m0[0] - m), e1 = __expf(m0[1] - m);
        float e2 = __expf(m0[2] - m), e3 = __expf(m0[3] - m);
        float e4 = __expf(m1[0] - m), e5 = __expf(m1[1] - m);
        float e6 = __expf(m1[2] - m), e7 = __expf(m1[3] - m);
        float inv = 1.0f / (e0 * s0[0] + e1 * s0[1] + e2 * s0[2] + e3 * s0[3] +
                            e4 * s1[0] + e5 * s1[1] + e6 * s1[2] + e7 * s1[3]);
        sc[0][tid] = e0 * inv; sc[1][tid] = e1 * inv;
        sc[2][tid] = e2 * inv; sc[3][tid] = e3 * inv;
        sc[4][tid] = e4 * inv; sc[5][tid] = e5 * inv;
        sc[6][tid] = e6 * inv; sc[7][tid] = e7 * inv;
    }
    __syncthreads();

    // ---- stage 1: X strip into Xs, 4 d-chunks of 128 ----
#pragma unroll 1
    for (int c = 0; c < 4; ++c) {
        const int d0 = c * 128;
        f32x4 acc[2][4] = {};
        for (int k0 = 0; k0 < L_; k0 += 32) {
            {  // A: P rows 64x32, 4 groups, 1/wave
                int r = wave * 16 + (lane >> 2);
                int cg = SW(r, lane & 3);
                async_cp16(Pb + (size_t)(l0 + r) * L_ + k0 + cg * 8, (char*)As + wave * 1024);
            }
#pragma unroll
            for (int h = 0; h < 2; ++h) {  // B: Vt rows 128x32, 8 groups, 2/wave
                int g = wave * 2 + h;
                int r = g * 16 + (lane >> 2);
                int cg = SW(r, lane & 3);
                async_cp16(Vt + (size_t)(d0 + r) * L_ + k0 + cg * 8, (char*)Bs + g * 1024);
            }
            __syncthreads();
            const int gk = k0 >> 6;
            half8 af[2], bf[4];
#pragma unroll
            for (int mi = 0; mi < 2; ++mi) {
                int r = wm + mi * 16 + lr;
                h16 s = (h16)sc[gk][r];
                half8 s8 = {s, s, s, s, s, s, s, s};
                af[mi] = *(const half8*)&As[r * 32 + SW(r, q) * 8] * s8;
            }
#pragma unroll
            for (int ni = 0; ni < 4; ++ni) {
                int r = wn + ni * 16 + lr;
                bf[ni] = *(const half8*)&Bs[r * 32 + SW(r, q) * 8];
            }
#pragma unroll
            for (int mi = 0; mi < 2; ++mi)
#pragma unroll
                for (int ni = 0; ni < 4; ++ni)
                    acc[mi][ni] = __builtin_amdgcn_mfma_f32_16x16x32_f16(af[mi], bf[ni], acc[mi][ni], 0, 0, 0);
            __syncthreads();
        }
        // epilogue: |Oh - acc| -> Xs
#pragma unroll
        for (int mi = 0; mi < 2; ++mi)
#pragma unroll
            for (int ni = 0; ni < 4; ++ni) {
                int row = wm + mi * 16 + q * 4;
                int col = wn + ni * 16 + lr;
#pragma unroll
                for (int r4 = 0; r4 < 4; ++r4) {
                    float x = fabsf(h2f(Oh[(size_t)(l0 + row + r4) * D_ + d0 + col]) -
                                    acc[mi][ni][r4]);
                    Xs[row + r4][d0 + col] = f2h(x);
                }
            }
    }
    __syncthreads();  // all Xs writes visible before stage 2 reads

    // ---- stage 2: out += tanh(Xs . W^T + b), 4 h-chunks of 128 ----
    const int bb = b;
#pragma unroll 1
    for (int c = 0; c < 4; ++c) {
        const int h0 = c * 128;
        f32x4 acc[2][4] = {};
        for (int k0 = 0; k0 < D_; k0 += 32) {
#pragma unroll
            for (int h = 0; h < 2; ++h) {  // B: Wt rows 128x32
                int g = wave * 2 + h;
                int r = g * 16 + (lane >> 2);
                int cg = SW(r, lane & 3);
                async_cp16(Wt + (size_t)(h0 + r) * D_ + k0 + cg * 8, (char*)Bs + g * 1024);
            }
            __syncthreads();
            half8 af[2], bf[4];
#pragma unroll
            for (int mi = 0; mi < 2; ++mi) {
                int r = wm + mi * 16 + lr;
                af[mi] = *(const half8*)&Xs[r][k0 + q * 8];  // resident, 16B-aligned
            }
#pragma unroll
            for (int ni = 0; ni < 4; ++ni) {
                int r = wn + ni * 16 + lr;
                bf[ni] = *(const half8*)&Bs[r * 32 + SW(r, q) * 8];
            }
#pragma unroll
            for (int mi = 0; mi < 2; ++mi)
#pragma unroll
                for (int ni = 0; ni < 4; ++ni)
                    acc[mi][ni] = __builtin_amdgcn_mfma_f32_16x16x32_f16(af[mi], bf[ni], acc[mi][ni], 0, 0, 0);
            __syncthreads();
        }
        // epilogue: fast_tanh + column reduce + atomics
#pragma unroll
        for (int ni = 0; ni < 4; ++ni) {
            int hcol = h0 + wn + ni * 16 + lr;
            float bsv = bias[hcol];
            float ssum = 0.f;
#pragma unroll
            for (int mi = 0; mi < 2; ++mi)
#pragma unroll
                for (int r4 = 0; r4 < 4; ++r4)
                    ssum += fast_tanh(acc[mi][ni][r4] + bsv);
            ssum += __shfl_xor(ssum, 16);
            ssum += __shfl_xor(ssum, 32);
            if (q == 0) atomicAdd(&out[bb * H_ + hcol], ssum * (0.5f / (float)L_));
        }
    }
}

extern "C" void kernel_launch(void* const* d_in, const int* in_sizes, int n_in,
                              void* d_out, int out_size, void* d_ws, size_t ws_size,
                              hipStream_t stream) {
    const float* I = (const float*)d_in[0];
    const float* Jm = (const float*)d_in[1];
    const float* W = (const float*)d_in[2];
    const float* bias = (const float*)d_in[3];
    float* out = (float*)d_out;

    const size_t BLD = (size_t)B_ * L_ * D_;
    const size_t BLL = (size_t)B_ * L_ * L_;

    char* p = (char*)d_ws;
    auto give = [&](size_t bytes) {
        char* r = p;
        p += (bytes + 255) & ~(size_t)255;
        return r;
    };
    u16* Ih = (u16*)give(BLD * 2);
    u16* Jh = (u16*)give(BLD * 2);
    u16* IhT = (u16*)give(BLD * 2);
    u16* JhT = (u16*)give(BLD * 2);
    u16* WT = (u16*)give((size_t)D_ * H_ * 2);
    u16* P_un = (u16*)give(BLL * 2);
    u16* P_unT = (u16*)give(BLL * 2);
    float* rtmax = (float*)give((size_t)B_ * L_ * 8 * 4);
    float* rtsum = (float*)give((size_t)B_ * L_ * 8 * 4);
    float* ctmax = (float*)give((size_t)B_ * L_ * 8 * 4);
    float* ctsum = (float*)give((size_t)B_ * L_ * 8 * 4);

    cvt_all<<<dim3(8, 8, 65), 256, 0, stream>>>(I, Jm, W, Ih, IhT, Jh, JhT, WT, out);
    score_mfma<<<512, 256, 0, stream>>>(Ih, Jh, P_un, P_unT, rtmax, rtsum, ctmax, ctsum);
    fused_tail<<<512, 256, 0, stream>>>(P_un, P_unT, rtmax, rtsum, ctmax, ctsum,
                                        JhT, IhT, Ih, Jh, WT, bias, out);
}

// Round 11
// 189.707 us; speedup vs baseline: 1.1588x; 1.1588x over previous
//
#include <hip/hip_runtime.h>
#include <math.h>

#define B_ 32
#define L_ 512
#define D_ 512
#define H_ 512

typedef unsigned short u16;
typedef _Float16 h16;
typedef h16 half8 __attribute__((ext_vector_type(8)));
typedef float f32x4 __attribute__((ext_vector_type(4)));

// chunk swizzle: 16B chunks within a 64B LDS row, XOR by (row>>1)&3.
#define SW(r, c) ((c) ^ (((r) >> 1) & 3))

typedef __attribute__((address_space(1))) void gvoid;
typedef __attribute__((address_space(3))) void svoid;
__device__ __forceinline__ void async_cp16(const void* g, void* l) {
    __builtin_amdgcn_global_load_lds((gvoid*)g, (svoid*)l, 16, 0, 0);
}

__device__ __forceinline__ u16 f2h(float x) {
    h16 h = (h16)x;
    u16 r;
    __builtin_memcpy(&r, &h, 2);
    return r;
}
__device__ __forceinline__ float h2f(u16 u) {
    h16 h;
    __builtin_memcpy(&h, &u, 2);
    return (float)h;
}
// tanh(x) = 1 - 2/(exp(2x)+1); exact at +-inf, err < 2e-6 vs libm
__device__ __forceinline__ float fast_tanh(float x) {
    return 1.0f - 2.0f / (__expf(2.0f * x) + 1.0f);
}

// XCD-aware decode (round-robin heuristic): 16 tiles of one z-slice on one XCD.
__device__ __forceinline__ void xcd_decode16(int n, int& z, int& tile) {
    int xcd = n & 7, w = n >> 3;
    z = xcd + 8 * (w >> 4);
    tile = w & 15;
}

// ---------------------------------------------------------------------------
// one dispatch: fp32->fp16 convert(+transpose) for I (z<32), J (32<=z<64),
// W (z==64, transposed only). z==64 blocks also zero the output buffer.
// ---------------------------------------------------------------------------
__global__ __launch_bounds__(256) void cvt_all(const float* __restrict__ I,
                                               const float* __restrict__ Jm,
                                               const float* __restrict__ W,
                                               u16* __restrict__ Ih, u16* __restrict__ IhT,
                                               u16* __restrict__ Jh, u16* __restrict__ JhT,
                                               u16* __restrict__ WT,
                                               float* __restrict__ out) {
    const int z = blockIdx.z;
    const float* src;
    u16* h;
    u16* hT;
    size_t base;
    if (z < 32) {
        src = I; h = Ih; hT = IhT; base = (size_t)z * 512 * 512;
    } else if (z < 64) {
        src = Jm; h = Jh; hT = JhT; base = (size_t)(z - 32) * 512 * 512;
    } else {
        src = W; h = nullptr; hT = WT; base = 0;
        out[(blockIdx.y * 8 + blockIdx.x) * 256 + threadIdx.x] = 0.0f;
    }
    const int r0 = blockIdx.y * 64, c0 = blockIdx.x * 64;
    __shared__ u16 t[64][66];
    const int tid = threadIdx.x;
    const int tr = tid >> 4, tc4 = (tid & 15) * 4;
#pragma unroll
    for (int rep = 0; rep < 4; ++rep) {
        int r = rep * 16 + tr;
        f32x4 v = *(const f32x4*)(src + base + (size_t)(r0 + r) * 512 + c0 + tc4);
        unsigned h0 = f2h(v[0]), h1 = f2h(v[1]), h2 = f2h(v[2]), h3 = f2h(v[3]);
        if (h)
            *(uint2*)(h + base + (size_t)(r0 + r) * 512 + c0 + tc4) =
                make_uint2(h0 | (h1 << 16), h2 | (h3 << 16));
        t[r][tc4] = (u16)h0; t[r][tc4 + 1] = (u16)h1;
        t[r][tc4 + 2] = (u16)h2; t[r][tc4 + 3] = (u16)h3;
    }
    __syncthreads();
#pragma unroll
    for (int rep = 0; rep < 4; ++rep) {
        int r = rep * 16 + tr;
        unsigned a = t[tc4][r], b = t[tc4 + 1][r], c = t[tc4 + 2][r], d = t[tc4 + 3][r];
        *(uint2*)(hT + base + (size_t)(c0 + r) * 512 + r0 + tc4) =
            make_uint2(a | (b << 16), c | (d << 16));
    }
}

// ---------------------------------------------------------------------------
// score: S = I.J^T fp16 MFMA. Epilogue writes P_un = fp16(exp(S - rtmax)),
// P_unT = fp16(exp(S - ctmax)), + group stat arrays [b][512][8].
// ---------------------------------------------------------------------------
__global__ __launch_bounds__(256, 2) void score_mfma(const u16* __restrict__ Ih,
                                                     const u16* __restrict__ Jh,
                                                     u16* __restrict__ P_un,
                                                     u16* __restrict__ P_unT,
                                                     float* __restrict__ rtmax,
                                                     float* __restrict__ rtsum,
                                                     float* __restrict__ ctmax,
                                                     float* __restrict__ ctsum) {
    int b, tile;
    xcd_decode16(blockIdx.x, b, tile);  // 512 blocks: 32 b x 16 tiles
    const int i0 = (tile >> 2) * 128, j0 = (tile & 3) * 128;
    __shared__ u16 Ah[128 * 32], Bh[128 * 32];
    const int tid = threadIdx.x;
    const int wave = tid >> 6, lane = tid & 63;
    const int wm = (wave >> 1) * 64, wn = (wave & 1) * 64;
    const int lr = lane & 15, q = lane >> 4;
    const size_t boff = (size_t)b * L_ * D_;
    const u16* Ibh = Ih + boff;
    const u16* Jbh = Jh + boff;

    f32x4 acc[4][4] = {};

    for (int k0 = 0; k0 < D_; k0 += 32) {
#pragma unroll
        for (int h = 0; h < 2; ++h) {
            int g = wave * 2 + h;
            int r = g * 16 + (lane >> 2);
            int cg = SW(r, lane & 3);
            async_cp16(Ibh + (size_t)(i0 + r) * D_ + k0 + cg * 8, (char*)Ah + g * 1024);
            async_cp16(Jbh + (size_t)(j0 + r) * D_ + k0 + cg * 8, (char*)Bh + g * 1024);
        }
        __syncthreads();
        half8 af[4], bf[4];
#pragma unroll
        for (int mi = 0; mi < 4; ++mi) {
            int r = wm + mi * 16 + lr;
            af[mi] = *(const half8*)&Ah[r * 32 + SW(r, q) * 8];
        }
#pragma unroll
        for (int ni = 0; ni < 4; ++ni) {
            int r = wn + ni * 16 + lr;
            bf[ni] = *(const half8*)&Bh[r * 32 + SW(r, q) * 8];
        }
#pragma unroll
        for (int mi = 0; mi < 4; ++mi)
#pragma unroll
            for (int ni = 0; ni < 4; ++ni)
                acc[mi][ni] = __builtin_amdgcn_mfma_f32_16x16x32_f16(af[mi], bf[ni], acc[mi][ni], 0, 0, 0);
        __syncthreads();
    }

    // ---- epilogue: group stats + P_un / P_unT ----
    float rm[4][4];
#pragma unroll
    for (int mi = 0; mi < 4; ++mi)
#pragma unroll
        for (int r4 = 0; r4 < 4; ++r4) {
            float t = fmaxf(fmaxf(acc[mi][0][r4], acc[mi][1][r4]),
                            fmaxf(acc[mi][2][r4], acc[mi][3][r4]));
#pragma unroll
            for (int off = 1; off < 16; off <<= 1) t = fmaxf(t, __shfl_xor(t, off));
            rm[mi][r4] = t;
        }
    float cm[4];
#pragma unroll
    for (int ni = 0; ni < 4; ++ni) {
        float u = -1e30f;
#pragma unroll
        for (int mi = 0; mi < 4; ++mi)
#pragma unroll
            for (int r4 = 0; r4 < 4; ++r4) u = fmaxf(u, acc[mi][ni][r4]);
        u = fmaxf(u, __shfl_xor(u, 16));
        u = fmaxf(u, __shfl_xor(u, 32));
        cm[ni] = u;
    }

    u16* Pu_b = P_un + (size_t)b * L_ * L_;
    u16* PuT_b = P_unT + (size_t)b * L_ * L_;
    float rs[4][4] = {};
    float cs[4] = {};
#pragma unroll
    for (int mi = 0; mi < 4; ++mi)
#pragma unroll
        for (int ni = 0; ni < 4; ++ni) {
            int i_base = i0 + wm + mi * 16 + q * 4;
            int j = j0 + wn + ni * 16 + lr;
            unsigned pc[4];
#pragma unroll
            for (int r4 = 0; r4 < 4; ++r4) {
                float er = __expf(acc[mi][ni][r4] - rm[mi][r4]);
                rs[mi][r4] += er;
                Pu_b[(size_t)(i_base + r4) * L_ + j] = f2h(er);
                float ec = __expf(acc[mi][ni][r4] - cm[ni]);
                cs[ni] += ec;
                pc[r4] = f2h(ec);
            }
            *(uint2*)&PuT_b[(size_t)j * L_ + i_base] =
                make_uint2(pc[0] | (pc[1] << 16), pc[2] | (pc[3] << 16));
        }

    const int gr = (j0 + wn) >> 6;
    const int gc = (i0 + wm) >> 6;
#pragma unroll
    for (int mi = 0; mi < 4; ++mi)
#pragma unroll
        for (int r4 = 0; r4 < 4; ++r4) {
            float s = rs[mi][r4];
#pragma unroll
            for (int off = 1; off < 16; off <<= 1) s += __shfl_xor(s, off);
            if (lr == 0) {
                int i = i0 + wm + mi * 16 + q * 4 + r4;
                rtmax[((size_t)b * L_ + i) * 8 + gr] = rm[mi][r4];
                rtsum[((size_t)b * L_ + i) * 8 + gr] = s;
            }
        }
#pragma unroll
    for (int ni = 0; ni < 4; ++ni) {
        float s = cs[ni];
        s += __shfl_xor(s, 16);
        s += __shfl_xor(s, 32);
        if (q == 0) {
            int j = j0 + wn + ni * 16 + lr;
            ctmax[((size_t)b * L_ + j) * 8 + gc] = cm[ni];
            ctsum[((size_t)b * L_ + j) * 8 + gc] = s;
        }
    }
}

// ---------------------------------------------------------------------------
// X = | Oh - softmax . V | fp16, both sides (zz = side*32+b). 128x128 tiles.
// Scale table TRANSPOSED: sc[8][128] -> K-loop reads sc[gk][r] hit 16
// consecutive banks with quarter-broadcast = conflict-free.
// ---------------------------------------------------------------------------
__global__ __launch_bounds__(256, 2) void absdiff_scaled(const u16* __restrict__ P_un,
                                                         const u16* __restrict__ P_unT,
                                                         const float* __restrict__ rtmax,
                                                         const float* __restrict__ rtsum,
                                                         const float* __restrict__ ctmax,
                                                         const float* __restrict__ ctsum,
                                                         const u16* __restrict__ JhT,
                                                         const u16* __restrict__ IhT,
                                                         const u16* __restrict__ Ih,
                                                         const u16* __restrict__ Jh,
                                                         u16* __restrict__ Xall) {
    int zz, tile;
    xcd_decode16(blockIdx.x, zz, tile);  // 1024 blocks: 64 zz x 16 tiles
    const int side = zz >> 5, b = zz & 31;
    const int a0 = (tile >> 2) * 128, d0 = (tile & 3) * 128;
    const u16* Pb = (side ? P_unT : P_un) + (size_t)b * L_ * L_;
    const float* tmax = (side ? ctmax : rtmax) + (size_t)b * L_ * 8;
    const float* tsum = (side ? ctsum : rtsum) + (size_t)b * L_ * 8;
    const u16* Vt = (side ? IhT : JhT) + (size_t)b * D_ * L_;
    const u16* Oh = (side ? Jh : Ih) + (size_t)b * L_ * D_;
    u16* Xb = Xall + (size_t)zz * L_ * D_;

    __shared__ u16 As[128 * 32], Bs[128 * 32];
    __shared__ float sc[8][128];  // transposed: conflict-free gk-major reads
    const int tid = threadIdx.x;
    const int wave = tid >> 6, lane = tid & 63;
    const int wm = (wave >> 1) * 64, wn = (wave & 1) * 64;
    const int lr = lane & 15, q = lane >> 4;

    // prologue: combine 8 group stats -> per-row scale table
    if (tid < 128) {
        const float* tm = tmax + (size_t)(a0 + tid) * 8;
        const float* ts = tsum + (size_t)(a0 + tid) * 8;
        f32x4 m0 = *(const f32x4*)tm, m1 = *(const f32x4*)(tm + 4);
        f32x4 s0 = *(const f32x4*)ts, s1 = *(const f32x4*)(ts + 4);
        float m = fmaxf(fmaxf(fmaxf(m0[0], m0[1]), fmaxf(m0[2], m0[3])),
                        fmaxf(fmaxf(m1[0], m1[1]), fmaxf(m1[2], m1[3])));
        float e0 = __expf(m0[0] - m), e1 = __expf(m0[1] - m);
        float e2 = __expf(m0[2] - m), e3 = __expf(m0[3] - m);
        float e4 = __expf(m1[0] - m), e5 = __expf(m1[1] - m);
        float e6 = __expf(m1[2] - m), e7 = __expf(m1[3] - m);
        float inv = 1.0f / (e0 * s0[0] + e1 * s0[1] + e2 * s0[2] + e3 * s0[3] +
                            e4 * s1[0] + e5 * s1[1] + e6 * s1[2] + e7 * s1[3]);
        sc[0][tid] = e0 * inv; sc[1][tid] = e1 * inv;
        sc[2][tid] = e2 * inv; sc[3][tid] = e3 * inv;
        sc[4][tid] = e4 * inv; sc[5][tid] = e5 * inv;
        sc[6][tid] = e6 * inv; sc[7][tid] = e7 * inv;
    }
    __syncthreads();

    f32x4 acc[4][4] = {};

    for (int k0 = 0; k0 < L_; k0 += 32) {
#pragma unroll
        for (int h = 0; h < 2; ++h) {
            int g = wave * 2 + h;
            int r = g * 16 + (lane >> 2);
            int cg = SW(r, lane & 3);
            async_cp16(Pb + (size_t)(a0 + r) * L_ + k0 + cg * 8, (char*)As + g * 1024);
            async_cp16(Vt + (size_t)(d0 + r) * L_ + k0 + cg * 8, (char*)Bs + g * 1024);
        }
        __syncthreads();
        const int gk = k0 >> 6;
        half8 af[4], bf[4];
#pragma unroll
        for (int mi = 0; mi < 4; ++mi) {
            int r = wm + mi * 16 + lr;
            h16 s = (h16)sc[gk][r];
            half8 s8 = {s, s, s, s, s, s, s, s};
            af[mi] = *(const half8*)&As[r * 32 + SW(r, q) * 8] * s8;
        }
#pragma unroll
        for (int ni = 0; ni < 4; ++ni) {
            int r = wn + ni * 16 + lr;
            bf[ni] = *(const half8*)&Bs[r * 32 + SW(r, q) * 8];
        }
#pragma unroll
        for (int mi = 0; mi < 4; ++mi)
#pragma unroll
            for (int ni = 0; ni < 4; ++ni)
                acc[mi][ni] = __builtin_amdgcn_mfma_f32_16x16x32_f16(af[mi], bf[ni], acc[mi][ni], 0, 0, 0);
        __syncthreads();
    }

#pragma unroll
    for (int mi = 0; mi < 4; ++mi)
#pragma unroll
        for (int ni = 0; ni < 4; ++ni) {
            int i = a0 + wm + mi * 16 + q * 4;
            int d = d0 + wn + ni * 16 + lr;
#pragma unroll
            for (int r4 = 0; r4 < 4; ++r4) {
                float x = fabsf(h2f(Oh[(size_t)(i + r4) * D_ + d]) - acc[mi][ni][r4]);
                Xb[(size_t)(i + r4) * D_ + d] = f2h(x);
            }
        }
}

// ---------------------------------------------------------------------------
// agg: out[b,h] += (0.5/L) * sum_l tanh( X[l,:].W[:,h] + bias[h] )
// 128x128 tiles, fast_tanh epilogue.
// ---------------------------------------------------------------------------
__global__ __launch_bounds__(256, 2) void agg_mfma(const u16* __restrict__ Xall,
                                                   const u16* __restrict__ Wt,
                                                   const float* __restrict__ bias,
                                                   float* __restrict__ out) {
    int zz, tile;
    xcd_decode16(blockIdx.x, zz, tile);  // 1024 blocks: 64 zz x 16 tiles
    const int bb = zz & 31;
    const u16* Xb = Xall + (size_t)zz * L_ * D_;
    const int l0 = (tile >> 2) * 128, h0 = (tile & 3) * 128;
    __shared__ u16 As[128 * 32], Bs[128 * 32];
    const int tid = threadIdx.x;
    const int wave = tid >> 6, lane = tid & 63;
    const int wm = (wave >> 1) * 64, wn = (wave & 1) * 64;
    const int lr = lane & 15, q = lane >> 4;

    f32x4 acc[4][4] = {};

    for (int k0 = 0; k0 < D_; k0 += 32) {
#pragma unroll
        for (int h = 0; h < 2; ++h) {
            int g = wave * 2 + h;
            int r = g * 16 + (lane >> 2);
            int cg = SW(r, lane & 3);
            async_cp16(Xb + (size_t)(l0 + r) * D_ + k0 + cg * 8, (char*)As + g * 1024);
            async_cp16(Wt + (size_t)(h0 + r) * D_ + k0 + cg * 8, (char*)Bs + g * 1024);
        }
        __syncthreads();
        half8 af[4], bf[4];
#pragma unroll
        for (int mi = 0; mi < 4; ++mi) {
            int r = wm + mi * 16 + lr;
            af[mi] = *(const half8*)&As[r * 32 + SW(r, q) * 8];
        }
#pragma unroll
        for (int ni = 0; ni < 4; ++ni) {
            int r = wn + ni * 16 + lr;
            bf[ni] = *(const half8*)&Bs[r * 32 + SW(r, q) * 8];
        }
#pragma unroll
        for (int mi = 0; mi < 4; ++mi)
#pragma unroll
            for (int ni = 0; ni < 4; ++ni)
                acc[mi][ni] = __builtin_amdgcn_mfma_f32_16x16x32_f16(af[mi], bf[ni], acc[mi][ni], 0, 0, 0);
        __syncthreads();
    }

#pragma unroll
    for (int ni = 0; ni < 4; ++ni) {
        int hcol = h0 + wn + ni * 16 + lr;
        float bsv = bias[hcol];
        float ssum = 0.f;
#pragma unroll
        for (int mi = 0; mi < 4; ++mi)
#pragma unroll
            for (int r4 = 0; r4 < 4; ++r4)
                ssum += fast_tanh(acc[mi][ni][r4] + bsv);
        ssum += __shfl_xor(ssum, 16);
        ssum += __shfl_xor(ssum, 32);
        if (q == 0) atomicAdd(&out[bb * H_ + hcol], ssum * (0.5f / (float)L_));
    }
}

extern "C" void kernel_launch(void* const* d_in, const int* in_sizes, int n_in,
                              void* d_out, int out_size, void* d_ws, size_t ws_size,
                              hipStream_t stream) {
    const float* I = (const float*)d_in[0];
    const float* Jm = (const float*)d_in[1];
    const float* W = (const float*)d_in[2];
    const float* bias = (const float*)d_in[3];
    float* out = (float*)d_out;

    const size_t BLD = (size_t)B_ * L_ * D_;
    const size_t BLL = (size_t)B_ * L_ * L_;

    char* p = (char*)d_ws;
    auto give = [&](size_t bytes) {
        char* r = p;
        p += (bytes + 255) & ~(size_t)255;
        return r;
    };
    u16* Ih = (u16*)give(BLD * 2);
    u16* Jh = (u16*)give(BLD * 2);
    u16* IhT = (u16*)give(BLD * 2);
    u16* JhT = (u16*)give(BLD * 2);
    u16* WT = (u16*)give((size_t)D_ * H_ * 2);
    u16* P_un = (u16*)give(BLL * 2);
    u16* P_unT = (u16*)give(BLL * 2);
    float* rtmax = (float*)give((size_t)B_ * L_ * 8 * 4);
    float* rtsum = (float*)give((size_t)B_ * L_ * 8 * 4);
    float* ctmax = (float*)give((size_t)B_ * L_ * 8 * 4);
    float* ctsum = (float*)give((size_t)B_ * L_ * 8 * 4);
    u16* Xall = (u16*)give(2 * BLD * 2);

    cvt_all<<<dim3(8, 8, 65), 256, 0, stream>>>(I, Jm, W, Ih, IhT, Jh, JhT, WT, out);
    score_mfma<<<512, 256, 0, stream>>>(Ih, Jh, P_un, P_unT, rtmax, rtsum, ctmax, ctsum);
    absdiff_scaled<<<1024, 256, 0, stream>>>(P_un, P_unT, rtmax, rtsum, ctmax, ctsum,
                                             JhT, IhT, Ih, Jh, Xall);
    agg_mfma<<<1024, 256, 0, stream>>>(Xall, WT, bias, out);
}